// Round 8
// baseline (431.960 us; speedup 1.0000x reference)
//
#include <hip/hip_runtime.h>
#include <hip/hip_bf16.h>

typedef unsigned short u16;
typedef __bf16 bf8 __attribute__((ext_vector_type(8)));
typedef float f4 __attribute__((ext_vector_type(4)));

__device__ __forceinline__ u16 f2bf(float f) {
    unsigned int u = __float_as_uint(f);
    u = (u + 0x7fffu + ((u >> 16) & 1u)) >> 16;   // RNE
    return (u16)u;
}

__device__ __forceinline__ void gload16(const u16* g, u16* l) {
    __builtin_amdgcn_global_load_lds((const __attribute__((address_space(1))) void*)g,
                                     (__attribute__((address_space(3))) void*)l, 16, 0, 0);
}

// ---------------- x fp32 -> bf16 ----------------
__global__ void cvt_x_kernel(const float* __restrict__ in, u16* __restrict__ out, int n4) {
    int i = blockIdx.x * blockDim.x + threadIdx.x;
    int stride = gridDim.x * blockDim.x;
    for (; i < n4; i += stride) {
        float4 v = ((const float4*)in)[i];
        ushort4 o;
        o.x = f2bf(v.x); o.y = f2bf(v.y); o.z = f2bf(v.z); o.w = f2bf(v.w);
        ((ushort4*)out)[i] = o;
    }
}

// ------------- [E][R][C] f32 -> [E][C][R] bf16 -------------
__global__ void transpose_cvt_kernel(const float* __restrict__ in, u16* __restrict__ out,
                                     int R, int C) {
    __shared__ float t[32][33];
    int e = blockIdx.z;
    int c0 = blockIdx.x * 32, r0 = blockIdx.y * 32;
    int tx = threadIdx.x & 31, ty = threadIdx.x >> 5;
    const float* ip = in + (size_t)e * R * C;
    u16* op = out + (size_t)e * R * C;
#pragma unroll
    for (int k = 0; k < 32; k += 8)
        t[ty + k][tx] = ip[(size_t)(r0 + ty + k) * C + c0 + tx];
    __syncthreads();
#pragma unroll
    for (int k = 0; k < 32; k += 8)
        op[(size_t)(c0 + ty + k) * R + r0 + tx] = f2bf(t[tx][ty + k]);
}

// ---------- S [7][1040][7] -> ST [1040][52] ----------
__global__ void transpose_S_kernel(const float* __restrict__ S, float* __restrict__ ST) {
    int idx = blockIdx.x * 256 + threadIdx.x;
    if (idx >= 1040 * 52) return;
    int d = idx / 52, c = idx % 52;
    ST[idx] = (c < 49) ? S[(c / 7) * 7280 + d * 7 + (c % 7)] : 0.f;
}

// ---------------- gating (fp32, exact semantics) ----------------
__global__ void gating_kernel(const float* __restrict__ x, const int* __restrict__ scene,
                              const float* __restrict__ ST, const float* __restrict__ semb,
                              float* __restrict__ gate) {
    __shared__ float xc[4][1040];
    __shared__ float Lsh[4][49];
    int wv = threadIdx.x >> 6, lane = threadIdx.x & 63;
    int row = blockIdx.x * 4 + wv;
    float* xcw = xc[wv];
    const float* xr = x + (size_t)row * 1024;
    for (int d = lane; d < 1024; d += 64) xcw[d] = xr[d];
    int sc = scene[row];
    if (lane < 16) xcw[1024 + lane] = semb[sc * 16 + lane];
    __syncthreads();

    if (lane < 49) {
        const float* STp = ST + lane;
        float a0 = 0.f, a1 = 0.f, a2 = 0.f, a3 = 0.f;
        for (int d = 0; d < 1040; d += 4) {
            a0 += xcw[d]     * STp[d * 52];
            a1 += xcw[d + 1] * STp[d * 52 + 52];
            a2 += xcw[d + 2] * STp[d * 52 + 104];
            a3 += xcw[d + 3] * STp[d * 52 + 156];
        }
        Lsh[wv][lane] = (a0 + a1) + (a2 + a3);
    }
    __syncthreads();

    if (lane == 0) {
        float logG[7][7], Gsc[7], piS[7], qS[7];
        for (int e = 0; e < 7; e++) {
            float L[7];
            float m = -1e30f;
            for (int s = 0; s < 7; s++) { L[s] = Lsh[wv][s * 7 + e]; m = fmaxf(m, L[s]); }
            float sum = 0.f;
            for (int s = 0; s < 7; s++) sum += expf(L[s] - m);
            float lse = m + logf(sum);
            float qs = 0.f;
            for (int s = 0; s < 7; s++) { logG[e][s] = L[s] - lse; qs += logG[e][s]; }
            piS[e] = logG[e][sc];
            qS[e] = qs;
            Gsc[e] = expf(logG[e][sc]);
        }
        int epi = 0, eqi = 0; float bp = piS[0], bq = qS[0];
        for (int e = 1; e < 7; e++) {
            if (piS[e] <= bp) { bp = piS[e]; epi = e; }
            if (qS[e]  <= bq) { bq = qS[e];  eqi = e; }
        }
        float mg = -1e30f;
        for (int e = 0; e < 7; e++) mg = fmaxf(mg, Gsc[e]);
        float sum = 0.f;
        float ex[7];
        for (int e = 0; e < 7; e++) { ex[e] = expf(Gsc[e] - mg); sum += ex[e]; }
        float inv = 1.f / sum;
        for (int e = 0; e < 7; e++) {
            float g = ex[e] * inv;
            if (e == epi && e == eqi) g = 0.f;
            gate[row * 7 + e] = g;
        }
    }
}

// ================= 256x256 deep-pipelined GEMM, one (expert, tile) per block =====
// BM=BN=256, BK=64, 512 thr (8 waves 2x4), per-wave 128x64.
// LDS: dbuf x (A[256][64] + B[256][64]) = 128 KB.
// Swizzle: elem col ^= (row&7)<<3 on global src + ds_read (conflicts = 0, R6-verified).
// T4 discipline: ALL 8 stages of tile gt+1 issued at phase 0 (full K-tile in flight),
// vmcnt(8) counted; per-phase counted lgkmcnt with sched_barrier-ordered read groups
// so group-2 LDS service hides under group-1 MFMA. vmcnt(0)/lgkmcnt(0) drains only
// at the final tile / per-phase tail.
template<bool G2>
__global__ __launch_bounds__(512, 2) void gemmE_kernel(
    const u16* __restrict__ Abase, const u16* __restrict__ Bbase,
    const float* __restrict__ bias, const float* __restrict__ gate,
    void* __restrict__ outp)
{
    constexpr int M = 4096;
    constexpr int K = G2 ? 2048 : 1024;
    constexpr int N = G2 ? 1024 : 2048;
    constexpr int NT = K / 64;
    constexpr int BNT = N / 256;           // 4 or 8 n-tiles

    extern __shared__ u16 lds[];

    const int tid = threadIdx.x;
    const int lane = tid & 63;
    const int wid = tid >> 6;
    const int wr = wid >> 2, wc = wid & 3;          // 2 x 4 waves
    const int ln15 = lane & 15, lnk = (lane >> 4) * 8;

    // bijective XCD chunk swizzle (nwg % 8 == 0)
    const int nwg = gridDim.x, cpx = nwg >> 3;
    const int wg = (blockIdx.x & 7) * cpx + (blockIdx.x >> 3);
    const int e  = wg / (16 * BNT);
    const int rem = wg % (16 * BNT);
    const int bm = rem / BNT, bn = rem % BNT;

    const u16* Ae = Abase + (G2 ? (size_t)e * M * K : (size_t)0);
    const u16* Be = Bbase + (size_t)e * N * K;

    const int sr = tid >> 3;              // 0..63
    const int sc = (tid & 7) * 8;

    auto stageA = [&](int kt, int buf) {
#pragma unroll
        for (int l = 0; l < 4; ++l) {
            int r = l * 64 + sr;
            int cs = sc ^ ((r & 7) << 3);
            const u16* g = Ae + (size_t)(bm * 256 + r) * K + kt * 64 + cs;
            gload16(g, lds + buf * 32768 + l * 4096 + tid * 8);
        }
    };
    auto stageB = [&](int kt, int buf, int h) {
#pragma unroll
        for (int l = 0; l < 2; ++l) {
            int rb = h * 128 + l * 64 + sr;
            int cs = sc ^ ((rb & 7) << 3);
            const u16* g = Be + (size_t)(bn * 256 + rb) * K + kt * 64 + cs;
            gload16(g, lds + buf * 32768 + 16384 + h * 8192 + l * 4096 + tid * 8);
        }
    };
    auto aoff = [&](int mi, int ks) {
        int r = wr * 128 + mi * 16 + ln15;
        int c = ks * 32 + lnk;
        return r * 64 + (c ^ ((r & 7) << 3));
    };
    auto boff = [&](int ni, int ks) {
        int rb = wc * 64 + ni * 16 + ln15;
        int c = ks * 32 + lnk;
        return rb * 64 + (c ^ ((rb & 7) << 3));
    };

    f4 acc[8][4] = {};
    bf8 aA[4][2], bL[2][2], bH[2][2];

    // prologue: tile 0 into buf 0 (8 loads)
    stageA(0, 0); stageB(0, 0, 0); stageB(0, 0, 1);

    for (int gt = 0; gt < NT; ++gt) {
        const int cur = gt & 1, nxt = cur ^ 1;
        const bool more = (gt + 1 < NT);
        const u16* Ac = lds + cur * 32768;
        const u16* Bc = lds + cur * 32768 + 16384;

        // ======== phase 0: stage ALL of tile gt+1, wait tile gt, Q(m-lo, n-lo)
        if (more) {
            stageA(gt + 1, nxt); stageB(gt + 1, nxt, 0); stageB(gt + 1, nxt, 1);
            asm volatile("s_waitcnt vmcnt(8)" ::: "memory");
        } else {
            asm volatile("s_waitcnt vmcnt(0)" ::: "memory");
        }
        __builtin_amdgcn_sched_barrier(0);
        __builtin_amdgcn_s_barrier();
        __builtin_amdgcn_sched_barrier(0);
        // group 1: bL (4 reads) + aA rows 0-1 (4 reads)
#pragma unroll
        for (int ni = 0; ni < 2; ++ni)
#pragma unroll
            for (int ks = 0; ks < 2; ++ks)
                bL[ni][ks] = *(const bf8*)(Bc + boff(ni, ks));
#pragma unroll
        for (int mi = 0; mi < 2; ++mi)
#pragma unroll
            for (int ks = 0; ks < 2; ++ks)
                aA[mi][ks] = *(const bf8*)(Ac + aoff(mi, ks));
        __builtin_amdgcn_sched_barrier(0);
        // group 2: aA rows 2-3 (4 reads)
#pragma unroll
        for (int mi = 2; mi < 4; ++mi)
#pragma unroll
            for (int ks = 0; ks < 2; ++ks)
                aA[mi][ks] = *(const bf8*)(Ac + aoff(mi, ks));
        asm volatile("s_waitcnt lgkmcnt(4)" ::: "memory");
        __builtin_amdgcn_sched_barrier(0);
        __builtin_amdgcn_s_setprio(1);
#pragma unroll
        for (int mi = 0; mi < 2; ++mi)
#pragma unroll
            for (int ni = 0; ni < 2; ++ni)
#pragma unroll
                for (int ks = 0; ks < 2; ++ks)
                    acc[mi][ni] = __builtin_amdgcn_mfma_f32_16x16x32_bf16(aA[mi][ks], bL[ni][ks], acc[mi][ni], 0, 0, 0);
        __builtin_amdgcn_s_setprio(0);
        asm volatile("s_waitcnt lgkmcnt(0)" ::: "memory");
        __builtin_amdgcn_sched_barrier(0);
        __builtin_amdgcn_s_setprio(1);
#pragma unroll
        for (int mi = 2; mi < 4; ++mi)
#pragma unroll
            for (int ni = 0; ni < 2; ++ni)
#pragma unroll
                for (int ks = 0; ks < 2; ++ks)
                    acc[mi][ni] = __builtin_amdgcn_mfma_f32_16x16x32_bf16(aA[mi][ks], bL[ni][ks], acc[mi][ni], 0, 0, 0);
        __builtin_amdgcn_s_setprio(0);

        // ======== phase 1: bH reads (counted), Q(m-lo, n-hi)
#pragma unroll
        for (int ks = 0; ks < 2; ++ks)
            bH[0][ks] = *(const bf8*)(Bc + boff(2, ks));
        __builtin_amdgcn_sched_barrier(0);
#pragma unroll
        for (int ks = 0; ks < 2; ++ks)
            bH[1][ks] = *(const bf8*)(Bc + boff(3, ks));
        asm volatile("s_waitcnt lgkmcnt(2)" ::: "memory");
        __builtin_amdgcn_sched_barrier(0);
        __builtin_amdgcn_s_setprio(1);
#pragma unroll
        for (int mi = 0; mi < 4; ++mi)
#pragma unroll
            for (int ks = 0; ks < 2; ++ks)
                acc[mi][2] = __builtin_amdgcn_mfma_f32_16x16x32_bf16(aA[mi][ks], bH[0][ks], acc[mi][2], 0, 0, 0);
        __builtin_amdgcn_s_setprio(0);
        asm volatile("s_waitcnt lgkmcnt(0)" ::: "memory");
        __builtin_amdgcn_sched_barrier(0);
        __builtin_amdgcn_s_setprio(1);
#pragma unroll
        for (int mi = 0; mi < 4; ++mi)
#pragma unroll
            for (int ks = 0; ks < 2; ++ks)
                acc[mi][3] = __builtin_amdgcn_mfma_f32_16x16x32_bf16(aA[mi][ks], bH[1][ks], acc[mi][3], 0, 0, 0);
        __builtin_amdgcn_s_setprio(0);

        // ======== phase 2: reload A m-hi (counted), Q(m-hi, n-hi)
#pragma unroll
        for (int mi = 0; mi < 2; ++mi)
#pragma unroll
            for (int ks = 0; ks < 2; ++ks)
                aA[mi][ks] = *(const bf8*)(Ac + aoff(4 + mi, ks));
        __builtin_amdgcn_sched_barrier(0);
#pragma unroll
        for (int mi = 2; mi < 4; ++mi)
#pragma unroll
            for (int ks = 0; ks < 2; ++ks)
                aA[mi][ks] = *(const bf8*)(Ac + aoff(4 + mi, ks));
        asm volatile("s_waitcnt lgkmcnt(4)" ::: "memory");
        __builtin_amdgcn_sched_barrier(0);
        __builtin_amdgcn_s_setprio(1);
#pragma unroll
        for (int mi = 0; mi < 2; ++mi)
#pragma unroll
            for (int ni = 2; ni < 4; ++ni)
#pragma unroll
                for (int ks = 0; ks < 2; ++ks)
                    acc[4 + mi][ni] = __builtin_amdgcn_mfma_f32_16x16x32_bf16(aA[mi][ks], bH[ni - 2][ks], acc[4 + mi][ni], 0, 0, 0);
        __builtin_amdgcn_s_setprio(0);
        asm volatile("s_waitcnt lgkmcnt(0)" ::: "memory");
        __builtin_amdgcn_sched_barrier(0);
        __builtin_amdgcn_s_setprio(1);
#pragma unroll
        for (int mi = 2; mi < 4; ++mi)
#pragma unroll
            for (int ni = 2; ni < 4; ++ni)
#pragma unroll
                for (int ks = 0; ks < 2; ++ks)
                    acc[4 + mi][ni] = __builtin_amdgcn_mfma_f32_16x16x32_bf16(aA[mi][ks], bH[ni - 2][ks], acc[4 + mi][ni], 0, 0, 0);
        __builtin_amdgcn_s_setprio(0);

        // ======== phase 3: barrier (buf[cur] free for gt+2), Q(m-hi, n-lo)
        __builtin_amdgcn_sched_barrier(0);
        __builtin_amdgcn_s_barrier();
        __builtin_amdgcn_sched_barrier(0);
        __builtin_amdgcn_s_setprio(1);
#pragma unroll
        for (int mi = 0; mi < 4; ++mi)
#pragma unroll
            for (int ni = 0; ni < 2; ++ni)
#pragma unroll
                for (int ks = 0; ks < 2; ++ks)
                    acc[4 + mi][ni] = __builtin_amdgcn_mfma_f32_16x16x32_bf16(aA[mi][ks], bL[ni][ks], acc[4 + mi][ni], 0, 0, 0);
        __builtin_amdgcn_s_setprio(0);
        __builtin_amdgcn_sched_barrier(0);
    }

    // ---------- epilogue
    float bloc[4];
#pragma unroll
    for (int ni = 0; ni < 4; ++ni)
        bloc[ni] = bias[e * N + bn * 256 + wc * 64 + ni * 16 + ln15];
    if constexpr (G2) {
        float* part = (float*)outp;
#pragma unroll
        for (int mi = 0; mi < 8; ++mi)
#pragma unroll
            for (int i = 0; i < 4; ++i) {
                int row = bm * 256 + wr * 128 + mi * 16 + (lane >> 4) * 4 + i;
                float g = gate[row * 7 + e];
#pragma unroll
                for (int ni = 0; ni < 4; ++ni) {
                    float v = g * fmaxf(acc[mi][ni][i] + bloc[ni], 0.f);
                    atomicAdd(&part[(size_t)row * N + bn * 256 + wc * 64 + ni * 16 + ln15], v);
                }
            }
    } else {
        u16* Hp = (u16*)outp + (size_t)e * M * N;
#pragma unroll
        for (int mi = 0; mi < 8; ++mi)
#pragma unroll
            for (int i = 0; i < 4; ++i) {
                size_t row = (size_t)(bm * 256 + wr * 128 + mi * 16 + (lane >> 4) * 4 + i);
#pragma unroll
                for (int ni = 0; ni < 4; ++ni)
                    Hp[row * N + bn * 256 + wc * 64 + ni * 16 + ln15] =
                        f2bf(fmaxf(acc[mi][ni][i] + bloc[ni], 0.f));
            }
    }
}

// ---------------- combine: out[t] = part, t = 0,1 ----------------
__global__ void combine_kernel(const float* __restrict__ part, float* __restrict__ out, int n4) {
    int i = blockIdx.x * blockDim.x + threadIdx.x;
    int stride = gridDim.x * blockDim.x;
    for (; i < n4; i += stride) {
        float4 v = ((const float4*)part)[i];
        ((float4*)out)[i] = v;
        ((float4*)out)[i + n4] = v;
    }
}

extern "C" void kernel_launch(void* const* d_in, const int* in_sizes, int n_in,
                              void* d_out, int out_size, void* d_ws, size_t ws_size,
                              hipStream_t stream) {
    const float* x     = (const float*)d_in[0];
    const int*   scene = (const int*)d_in[1];
    const float* W1    = (const float*)d_in[2];
    const float* b1    = (const float*)d_in[3];
    const float* W2    = (const float*)d_in[4];
    const float* b2    = (const float*)d_in[5];
    const float* S     = (const float*)d_in[6];
    const float* semb  = (const float*)d_in[7];
    float* out = (float*)d_out;

    char* ws = (char*)d_ws;
    float* part = (float*)(ws);                                // 16.8 MB, aliases xb (dead after gemm1)
    u16*   xb   = (u16*)(ws);                                  // 8,388,608 B
    u16*   W1T  = (u16*)(ws + 8388608);                        // 29,360,128 B
    u16*   W2T  = (u16*)(ws + 37748736);                       // 29,360,128 B
    u16*   Hb   = (u16*)(ws + 67108864);                       // 117,440,512 B
    float* gate = (float*)(ws + 184549376);                    // 114,688 B
    float* ST   = (float*)(ws + 184664064);                    // 216,320 B

    (void)hipFuncSetAttribute(reinterpret_cast<const void*>(gemmE_kernel<false>),
                              hipFuncAttributeMaxDynamicSharedMemorySize, 131072);
    (void)hipFuncSetAttribute(reinterpret_cast<const void*>(gemmE_kernel<true>),
                              hipFuncAttributeMaxDynamicSharedMemorySize, 131072);

    cvt_x_kernel<<<2048, 256, 0, stream>>>(x, xb, 4096 * 1024 / 4);
    transpose_cvt_kernel<<<dim3(64, 32, 7), 256, 0, stream>>>(W1, W1T, 1024, 2048);
    transpose_cvt_kernel<<<dim3(32, 64, 7), 256, 0, stream>>>(W2, W2T, 2048, 1024);
    transpose_S_kernel<<<(1040 * 52 + 255) / 256, 256, 0, stream>>>(S, ST);
    gating_kernel<<<1024, 256, 0, stream>>>(x, scene, ST, semb, gate);
    gemmE_kernel<false><<<896, 512, 131072, stream>>>(xb, W1T, b1, nullptr, Hb);
    (void)hipMemsetAsync(part, 0, (size_t)4096 * 1024 * 4, stream);
    gemmE_kernel<true><<<448, 512, 131072, stream>>>(Hb, W2T, b2, gate, part);
    combine_kernel<<<2048, 256, 0, stream>>>(part, out, 4096 * 1024 / 4);
}

// Round 9
// 384.171 us; speedup vs baseline: 1.1244x; 1.1244x over previous
//
#include <hip/hip_runtime.h>
#include <hip/hip_bf16.h>

typedef unsigned short u16;
typedef __bf16 bf8 __attribute__((ext_vector_type(8)));
typedef float f4 __attribute__((ext_vector_type(4)));

__device__ __forceinline__ u16 f2bf(float f) {
    unsigned int u = __float_as_uint(f);
    u = (u + 0x7fffu + ((u >> 16) & 1u)) >> 16;   // RNE
    return (u16)u;
}

__device__ __forceinline__ void gload16(const u16* g, u16* l) {
    __builtin_amdgcn_global_load_lds((const __attribute__((address_space(1))) void*)g,
                                     (__attribute__((address_space(3))) void*)l, 16, 0, 0);
}

// ---------------- x fp32 -> bf16 ----------------
__global__ void cvt_x_kernel(const float* __restrict__ in, u16* __restrict__ out, int n4) {
    int i = blockIdx.x * blockDim.x + threadIdx.x;
    int stride = gridDim.x * blockDim.x;
    for (; i < n4; i += stride) {
        float4 v = ((const float4*)in)[i];
        ushort4 o;
        o.x = f2bf(v.x); o.y = f2bf(v.y); o.z = f2bf(v.z); o.w = f2bf(v.w);
        ((ushort4*)out)[i] = o;
    }
}

// ------------- [E][R][C] f32 -> [E][C][R] bf16, 64x64 tiles -------------
// bf16 in LDS (odd stride 71 kills write conflicts); ushort2 coalesced stores.
__global__ void transpose_cvt_kernel(const float* __restrict__ in, u16* __restrict__ out,
                                     int R, int C) {
    __shared__ u16 t[64][71];
    int e = blockIdx.z;
    int c0 = blockIdx.x * 64, r0 = blockIdx.y * 64;
    int tid = threadIdx.x;
    const float* ip = in + (size_t)e * R * C;
    u16* op = out + (size_t)e * R * C;
#pragma unroll
    for (int k = 0; k < 16; ++k) {
        int idx = k * 256 + tid;
        int r = idx >> 6, c = idx & 63;
        t[c][r] = f2bf(ip[(size_t)(r0 + r) * C + c0 + c]);
    }
    __syncthreads();
#pragma unroll
    for (int k = 0; k < 8; ++k) {
        int c = k * 8 + (tid >> 5);
        int rr = (tid & 31) * 2;
        ushort2 v = make_ushort2(t[c][rr], t[c][rr + 1]);
        *(ushort2*)(op + (size_t)(c0 + c) * R + r0 + rr) = v;
    }
}

// ---------- S [7][1040][7] -> ST [1040][52] ----------
__global__ void transpose_S_kernel(const float* __restrict__ S, float* __restrict__ ST) {
    int idx = blockIdx.x * 256 + threadIdx.x;
    if (idx >= 1040 * 52) return;
    int d = idx / 52, c = idx % 52;
    ST[idx] = (c < 49) ? S[(c / 7) * 7280 + d * 7 + (c % 7)] : 0.f;
}

// ---------------- gating (fp32, exact semantics) ----------------
__global__ void gating_kernel(const float* __restrict__ x, const int* __restrict__ scene,
                              const float* __restrict__ ST, const float* __restrict__ semb,
                              float* __restrict__ gate) {
    __shared__ float xc[4][1040];
    __shared__ float Lsh[4][49];
    int wv = threadIdx.x >> 6, lane = threadIdx.x & 63;
    int row = blockIdx.x * 4 + wv;
    float* xcw = xc[wv];
    const float* xr = x + (size_t)row * 1024;
    for (int d = lane; d < 1024; d += 64) xcw[d] = xr[d];
    int sc = scene[row];
    if (lane < 16) xcw[1024 + lane] = semb[sc * 16 + lane];
    __syncthreads();

    if (lane < 49) {
        const float* STp = ST + lane;
        float a0 = 0.f, a1 = 0.f, a2 = 0.f, a3 = 0.f;
        for (int d = 0; d < 1040; d += 4) {
            a0 += xcw[d]     * STp[d * 52];
            a1 += xcw[d + 1] * STp[d * 52 + 52];
            a2 += xcw[d + 2] * STp[d * 52 + 104];
            a3 += xcw[d + 3] * STp[d * 52 + 156];
        }
        Lsh[wv][lane] = (a0 + a1) + (a2 + a3);
    }
    __syncthreads();

    if (lane == 0) {
        float logG[7][7], Gsc[7], piS[7], qS[7];
        for (int e = 0; e < 7; e++) {
            float L[7];
            float m = -1e30f;
            for (int s = 0; s < 7; s++) { L[s] = Lsh[wv][s * 7 + e]; m = fmaxf(m, L[s]); }
            float sum = 0.f;
            for (int s = 0; s < 7; s++) sum += expf(L[s] - m);
            float lse = m + logf(sum);
            float qs = 0.f;
            for (int s = 0; s < 7; s++) { logG[e][s] = L[s] - lse; qs += logG[e][s]; }
            piS[e] = logG[e][sc];
            qS[e] = qs;
            Gsc[e] = expf(logG[e][sc]);
        }
        int epi = 0, eqi = 0; float bp = piS[0], bq = qS[0];
        for (int e = 1; e < 7; e++) {
            if (piS[e] <= bp) { bp = piS[e]; epi = e; }
            if (qS[e]  <= bq) { bq = qS[e];  eqi = e; }
        }
        float mg = -1e30f;
        for (int e = 0; e < 7; e++) mg = fmaxf(mg, Gsc[e]);
        float sum = 0.f;
        float ex[7];
        for (int e = 0; e < 7; e++) { ex[e] = expf(Gsc[e] - mg); sum += ex[e]; }
        float inv = 1.f / sum;
        for (int e = 0; e < 7; e++) {
            float g = ex[e] * inv;
            if (e == epi && e == eqi) g = 0.f;
            gate[row * 7 + e] = g;
        }
    }
}

// ================= 8-phase GEMM template (R6-proven structure) =================
// BM=128, BN=256, BK=64, 512 thr (8 waves 2x4), per-wave 64x64.
// LDS per dbuf: A[128][64] + B[256][64]; 2 dbuf = 96KB.
// T2 swizzle (full 3-bit): elem col ^= (row&7)<<3; conflicts = 0 (R6-verified).
// Counted vmcnt: 6 loads/K-tile staged (4 at p0, 2 at p1); vmcnt(4) once per
// K-tile, vmcnt(0) only at final tile.
template<bool G2>
__global__ __launch_bounds__(512, 2) void gemm8p_kernel(
    const u16* __restrict__ Abase, const u16* __restrict__ Bbase,
    const float* __restrict__ bias, const float* __restrict__ gate,
    void* __restrict__ outp)
{
    constexpr int M = 4096;
    constexpr int K = G2 ? 2048 : 1024;
    constexpr int N = G2 ? 1024 : 2048;
    constexpr int NT = K / 64;
    constexpr int LOG2NT = G2 ? 5 : 4;

    extern __shared__ u16 lds[];

    const int tid = threadIdx.x;
    const int lane = tid & 63;
    const int wid = tid >> 6;
    const int wr = wid >> 2, wc = wid & 3;
    const int ln15 = lane & 15, lnk = (lane >> 4) * 8;

    int bm, bn, e0, nE, grp;
    if constexpr (G2) {
        int id = blockIdx.x;
        int xcd = id & 7, slot = id >> 3;
        grp = xcd & 1;
        bn = slot & 3;
        bm = (slot >> 2) * 4 + (xcd >> 1);
        e0 = grp * 4; nE = grp ? 3 : 4;
    } else {
        int id = blockIdx.x;
        e0 = id >> 8;
        bm = (id & 255) >> 3;
        bn = id & 7;
        nE = 1; grp = 0;
    }
    const int NTtot = nE * NT;

    const int sr = tid >> 3;          // staging row within 64-row sub-unit
    const int sc = (tid & 7) * 8;     // staging col (elems)

    auto stageA = [&](int gt, int buf) {
#pragma unroll
        for (int l = 0; l < 2; ++l) {
            int r = l * 64 + sr;
            int cs = sc ^ ((r & 7) << 3);
            const u16* g = Abase + (G2 ? (size_t)(e0 + (gt >> LOG2NT)) * M * K : (size_t)0)
                         + (size_t)(bm * 128 + r) * K + (gt & (NT - 1)) * 64 + cs;
            gload16(g, lds + buf * 24576 + l * 4096 + tid * 8);
        }
    };
    auto stageB = [&](int gt, int buf, int h) {
#pragma unroll
        for (int l = 0; l < 2; ++l) {
            int rb = h * 128 + l * 64 + sr;
            int cs = sc ^ ((rb & 7) << 3);
            const u16* g = Bbase + (size_t)(e0 + (gt >> LOG2NT)) * N * K
                         + (size_t)(bn * 256 + rb) * K + (gt & (NT - 1)) * 64 + cs;
            gload16(g, lds + buf * 24576 + 8192 + h * 8192 + l * 4096 + tid * 8);
        }
    };
    auto aoff = [&](int mi, int ks) {
        int r = wr * 64 + mi * 16 + ln15;
        int c = ks * 32 + lnk;
        return r * 64 + (c ^ ((r & 7) << 3));
    };
    auto boff = [&](int ni, int ks) {
        int rb = wc * 64 + ni * 16 + ln15;
        int c = ks * 32 + lnk;
        return rb * 64 + (c ^ ((rb & 7) << 3));
    };

    f4 acc[4][4] = {};
    f4 fin[4][4] = {};
    bf8 aA[2][2], bL[2][2], bH[2][2];

    // prologue: tile 0 into buf 0 (6 loads)
    stageA(0, 0); stageB(0, 0, 0); stageB(0, 0, 1);

    for (int gt = 0; gt < NTtot; ++gt) {
        const int cur = gt & 1, nxt = cur ^ 1;
        const bool more = (gt + 1 < NTtot);
        const u16* Ac = lds + cur * 24576;
        const u16* Bc = lds + cur * 24576 + 8192;
        // ---------- phase 0: stage(A',B0') + wait tile gt + Q(m-lo, n-lo)
        if (more) {
            stageA(gt + 1, nxt); stageB(gt + 1, nxt, 0);
            asm volatile("s_waitcnt vmcnt(4)" ::: "memory");
        } else {
            asm volatile("s_waitcnt vmcnt(0)" ::: "memory");
        }
        __builtin_amdgcn_sched_barrier(0);
        __builtin_amdgcn_s_barrier();
        __builtin_amdgcn_sched_barrier(0);
#pragma unroll
        for (int mi = 0; mi < 2; ++mi)
#pragma unroll
            for (int ks = 0; ks < 2; ++ks)
                aA[mi][ks] = *(const bf8*)(Ac + aoff(mi, ks));
#pragma unroll
        for (int ni = 0; ni < 2; ++ni)
#pragma unroll
            for (int ks = 0; ks < 2; ++ks)
                bL[ni][ks] = *(const bf8*)(Bc + boff(ni, ks));
        asm volatile("s_waitcnt lgkmcnt(0)" ::: "memory");
        __builtin_amdgcn_sched_barrier(0);
        __builtin_amdgcn_s_setprio(1);
#pragma unroll
        for (int mi = 0; mi < 2; ++mi)
#pragma unroll
            for (int ni = 0; ni < 2; ++ni)
#pragma unroll
                for (int ks = 0; ks < 2; ++ks)
                    acc[mi][ni] = __builtin_amdgcn_mfma_f32_16x16x32_bf16(aA[mi][ks], bL[ni][ks], acc[mi][ni], 0, 0, 0);
        __builtin_amdgcn_s_setprio(0);
        // ---------- phase 1: stage(B1') + Q(m-lo, n-hi)
        if (more) stageB(gt + 1, nxt, 1);
#pragma unroll
        for (int ni = 0; ni < 2; ++ni)
#pragma unroll
            for (int ks = 0; ks < 2; ++ks)
                bH[ni][ks] = *(const bf8*)(Bc + boff(2 + ni, ks));
        asm volatile("s_waitcnt lgkmcnt(0)" ::: "memory");
        __builtin_amdgcn_sched_barrier(0);
        __builtin_amdgcn_s_setprio(1);
#pragma unroll
        for (int mi = 0; mi < 2; ++mi)
#pragma unroll
            for (int ni = 0; ni < 2; ++ni)
#pragma unroll
                for (int ks = 0; ks < 2; ++ks)
                    acc[mi][2 + ni] = __builtin_amdgcn_mfma_f32_16x16x32_bf16(aA[mi][ks], bH[ni][ks], acc[mi][2 + ni], 0, 0, 0);
        __builtin_amdgcn_s_setprio(0);
        // ---------- phase 2: reload A (m-hi) + Q(m-hi, n-hi)
#pragma unroll
        for (int mi = 0; mi < 2; ++mi)
#pragma unroll
            for (int ks = 0; ks < 2; ++ks)
                aA[mi][ks] = *(const bf8*)(Ac + aoff(2 + mi, ks));
        asm volatile("s_waitcnt lgkmcnt(0)" ::: "memory");
        __builtin_amdgcn_sched_barrier(0);
        __builtin_amdgcn_s_setprio(1);
#pragma unroll
        for (int mi = 0; mi < 2; ++mi)
#pragma unroll
            for (int ni = 0; ni < 2; ++ni)
#pragma unroll
                for (int ks = 0; ks < 2; ++ks)
                    acc[2 + mi][2 + ni] = __builtin_amdgcn_mfma_f32_16x16x32_bf16(aA[mi][ks], bH[ni][ks], acc[2 + mi][2 + ni], 0, 0, 0);
        __builtin_amdgcn_s_setprio(0);
        // ---------- phase 3: barrier (protect buf[cur] before gt+2 stages) + Q(m-hi, n-lo)
        __builtin_amdgcn_sched_barrier(0);
        __builtin_amdgcn_s_barrier();
        __builtin_amdgcn_sched_barrier(0);
        __builtin_amdgcn_s_setprio(1);
#pragma unroll
        for (int mi = 0; mi < 2; ++mi)
#pragma unroll
            for (int ni = 0; ni < 2; ++ni)
#pragma unroll
                for (int ks = 0; ks < 2; ++ks)
                    acc[2 + mi][ni] = __builtin_amdgcn_mfma_f32_16x16x32_bf16(aA[mi][ks], bL[ni][ks], acc[2 + mi][ni], 0, 0, 0);
        __builtin_amdgcn_s_setprio(0);
        __builtin_amdgcn_sched_barrier(0);
        // ---------- expert boundary (G2): gate-weighted accumulate, reset acc
        if constexpr (G2) {
            if ((gt & (NT - 1)) == NT - 1) {
                int e = e0 + (gt >> LOG2NT);
                float bloc[4];
#pragma unroll
                for (int ni = 0; ni < 4; ++ni)
                    bloc[ni] = bias[e * N + bn * 256 + wc * 64 + ni * 16 + ln15];
#pragma unroll
                for (int mi = 0; mi < 4; ++mi)
#pragma unroll
                    for (int i = 0; i < 4; ++i) {
                        int row = bm * 128 + wr * 64 + mi * 16 + (lane >> 4) * 4 + i;
                        float g = gate[row * 7 + e];
#pragma unroll
                        for (int ni = 0; ni < 4; ++ni) {
                            fin[mi][ni][i] += g * fmaxf(acc[mi][ni][i] + bloc[ni], 0.f);
                            acc[mi][ni][i] = 0.f;
                        }
                    }
            }
        }
    }

    // ---------- final epilogue
    if constexpr (G2) {
        float* po = (float*)outp + (size_t)grp * M * N;
#pragma unroll
        for (int mi = 0; mi < 4; ++mi)
#pragma unroll
            for (int i = 0; i < 4; ++i) {
                size_t row = (size_t)(bm * 128 + wr * 64 + mi * 16 + (lane >> 4) * 4 + i);
#pragma unroll
                for (int ni = 0; ni < 4; ++ni)
                    po[row * N + bn * 256 + wc * 64 + ni * 16 + ln15] = fin[mi][ni][i];
            }
    } else {
        float bloc[4];
#pragma unroll
        for (int ni = 0; ni < 4; ++ni)
            bloc[ni] = bias[e0 * N + bn * 256 + wc * 64 + ni * 16 + ln15];
        u16* Hp = (u16*)outp + (size_t)e0 * M * N;
#pragma unroll
        for (int mi = 0; mi < 4; ++mi)
#pragma unroll
            for (int i = 0; i < 4; ++i) {
                size_t row = (size_t)(bm * 128 + wr * 64 + mi * 16 + (lane >> 4) * 4 + i);
#pragma unroll
                for (int ni = 0; ni < 4; ++ni) {
                    // non-temporal: keep the 117MB H stream out of L3 so A/B stay resident
                    __builtin_nontemporal_store(
                        f2bf(fmaxf(acc[mi][ni][i] + bloc[ni], 0.f)),
                        &Hp[row * N + bn * 256 + wc * 64 + ni * 16 + ln15]);
                }
            }
    }
}

// ---------------- combine: out[t] = p0 + p1, t = 0,1 ----------------
__global__ void combine_kernel(const float* __restrict__ p0, const float* __restrict__ p1,
                               float* __restrict__ out, int n4) {
    int i = blockIdx.x * blockDim.x + threadIdx.x;
    int stride = gridDim.x * blockDim.x;
    for (; i < n4; i += stride) {
        float4 a = ((const float4*)p0)[i];
        float4 b = ((const float4*)p1)[i];
        float4 v = make_float4(a.x + b.x, a.y + b.y, a.z + b.z, a.w + b.w);
        ((float4*)out)[i] = v;
        ((float4*)out)[i + n4] = v;
    }
}

extern "C" void kernel_launch(void* const* d_in, const int* in_sizes, int n_in,
                              void* d_out, int out_size, void* d_ws, size_t ws_size,
                              hipStream_t stream) {
    const float* x     = (const float*)d_in[0];
    const int*   scene = (const int*)d_in[1];
    const float* W1    = (const float*)d_in[2];
    const float* b1    = (const float*)d_in[3];
    const float* W2    = (const float*)d_in[4];
    const float* b2    = (const float*)d_in[5];
    const float* S     = (const float*)d_in[6];
    const float* semb  = (const float*)d_in[7];
    float* out = (float*)d_out;

    char* ws = (char*)d_ws;
    float* part = (float*)(ws);                                // 33.5 MB, aliases xb+W1T (dead after gemm1)
    u16*   xb   = (u16*)(ws);                                  // 8,388,608 B
    u16*   W1T  = (u16*)(ws + 8388608);                        // 29,360,128 B
    u16*   W2T  = (u16*)(ws + 37748736);                       // 29,360,128 B
    u16*   Hb   = (u16*)(ws + 67108864);                       // 117,440,512 B
    float* gate = (float*)(ws + 184549376);                    // 114,688 B
    float* ST   = (float*)(ws + 184664064);                    // 216,320 B

    (void)hipFuncSetAttribute(reinterpret_cast<const void*>(gemm8p_kernel<false>),
                              hipFuncAttributeMaxDynamicSharedMemorySize, 98304);
    (void)hipFuncSetAttribute(reinterpret_cast<const void*>(gemm8p_kernel<true>),
                              hipFuncAttributeMaxDynamicSharedMemorySize, 98304);

    cvt_x_kernel<<<2048, 256, 0, stream>>>(x, xb, 4096 * 1024 / 4);
    transpose_cvt_kernel<<<dim3(32, 16, 7), 256, 0, stream>>>(W1, W1T, 1024, 2048);
    transpose_cvt_kernel<<<dim3(16, 32, 7), 256, 0, stream>>>(W2, W2T, 2048, 1024);
    transpose_S_kernel<<<(1040 * 52 + 255) / 256, 256, 0, stream>>>(S, ST);
    gating_kernel<<<1024, 256, 0, stream>>>(x, scene, ST, semb, gate);
    gemm8p_kernel<false><<<1792, 512, 98304, stream>>>(xb, W1T, b1, nullptr, Hb);
    gemm8p_kernel<true><<<256, 512, 98304, stream>>>(Hb, W2T, b2, gate, part);
    combine_kernel<<<2048, 256, 0, stream>>>(part, part + 4096 * 1024, out, 4096 * 1024 / 4);
}

// Round 11
// 380.943 us; speedup vs baseline: 1.1339x; 1.0085x over previous
//
#include <hip/hip_runtime.h>
#include <hip/hip_bf16.h>

typedef unsigned short u16;
typedef __bf16 bf8 __attribute__((ext_vector_type(8)));
typedef float f4 __attribute__((ext_vector_type(4)));

__device__ __forceinline__ u16 f2bf(float f) {
    unsigned int u = __float_as_uint(f);
    u = (u + 0x7fffu + ((u >> 16) & 1u)) >> 16;   // RNE
    return (u16)u;
}

__device__ __forceinline__ void gload16(const u16* g, u16* l) {
    __builtin_amdgcn_global_load_lds((const __attribute__((address_space(1))) void*)g,
                                     (__attribute__((address_space(3))) void*)l, 16, 0, 0);
}

// ---------------- x fp32 -> bf16 ----------------
__global__ void cvt_x_kernel(const float* __restrict__ in, u16* __restrict__ out, int n4) {
    int i = blockIdx.x * blockDim.x + threadIdx.x;
    int stride = gridDim.x * blockDim.x;
    for (; i < n4; i += stride) {
        float4 v = ((const float4*)in)[i];
        ushort4 o;
        o.x = f2bf(v.x); o.y = f2bf(v.y); o.z = f2bf(v.z); o.w = f2bf(v.w);
        ((ushort4*)out)[i] = o;
    }
}

// ------------- [E][R][C] f32 -> [E][C][R] bf16, 64x64 tiles -------------
__global__ void transpose_cvt_kernel(const float* __restrict__ in, u16* __restrict__ out,
                                     int R, int C) {
    __shared__ u16 t[64][71];
    int e = blockIdx.z;
    int c0 = blockIdx.x * 64, r0 = blockIdx.y * 64;
    int tid = threadIdx.x;
    const float* ip = in + (size_t)e * R * C;
    u16* op = out + (size_t)e * R * C;
#pragma unroll
    for (int k = 0; k < 16; ++k) {
        int idx = k * 256 + tid;
        int r = idx >> 6, c = idx & 63;
        t[c][r] = f2bf(ip[(size_t)(r0 + r) * C + c0 + c]);
    }
    __syncthreads();
#pragma unroll
    for (int k = 0; k < 8; ++k) {
        int c = k * 8 + (tid >> 5);
        int rr = (tid & 31) * 2;
        ushort2 v = make_ushort2(t[c][rr], t[c][rr + 1]);
        *(ushort2*)(op + (size_t)(c0 + c) * R + r0 + rr) = v;
    }
}

// ---------- S [7][1040][7] -> ST [1040][52] ----------
__global__ void transpose_S_kernel(const float* __restrict__ S, float* __restrict__ ST) {
    int idx = blockIdx.x * 256 + threadIdx.x;
    if (idx >= 1040 * 52) return;
    int d = idx / 52, c = idx % 52;
    ST[idx] = (c < 49) ? S[(c / 7) * 7280 + d * 7 + (c % 7)] : 0.f;
}

// ---------------- gating (fp32, exact semantics) ----------------
__global__ void gating_kernel(const float* __restrict__ x, const int* __restrict__ scene,
                              const float* __restrict__ ST, const float* __restrict__ semb,
                              float* __restrict__ gate) {
    __shared__ float xc[4][1040];
    __shared__ float Lsh[4][49];
    int wv = threadIdx.x >> 6, lane = threadIdx.x & 63;
    int row = blockIdx.x * 4 + wv;
    float* xcw = xc[wv];
    const float* xr = x + (size_t)row * 1024;
    for (int d = lane; d < 1024; d += 64) xcw[d] = xr[d];
    int sc = scene[row];
    if (lane < 16) xcw[1024 + lane] = semb[sc * 16 + lane];
    __syncthreads();

    if (lane < 49) {
        const float* STp = ST + lane;
        float a0 = 0.f, a1 = 0.f, a2 = 0.f, a3 = 0.f;
        for (int d = 0; d < 1040; d += 4) {
            a0 += xcw[d]     * STp[d * 52];
            a1 += xcw[d + 1] * STp[d * 52 + 52];
            a2 += xcw[d + 2] * STp[d * 52 + 104];
            a3 += xcw[d + 3] * STp[d * 52 + 156];
        }
        Lsh[wv][lane] = (a0 + a1) + (a2 + a3);
    }
    __syncthreads();

    if (lane == 0) {
        float logG[7][7], Gsc[7], piS[7], qS[7];
        for (int e = 0; e < 7; e++) {
            float L[7];
            float m = -1e30f;
            for (int s = 0; s < 7; s++) { L[s] = Lsh[wv][s * 7 + e]; m = fmaxf(m, L[s]); }
            float sum = 0.f;
            for (int s = 0; s < 7; s++) sum += expf(L[s] - m);
            float lse = m + logf(sum);
            float qs = 0.f;
            for (int s = 0; s < 7; s++) { logG[e][s] = L[s] - lse; qs += logG[e][s]; }
            piS[e] = logG[e][sc];
            qS[e] = qs;
            Gsc[e] = expf(logG[e][sc]);
        }
        int epi = 0, eqi = 0; float bp = piS[0], bq = qS[0];
        for (int e = 1; e < 7; e++) {
            if (piS[e] <= bp) { bp = piS[e]; epi = e; }
            if (qS[e]  <= bq) { bq = qS[e];  eqi = e; }
        }
        float mg = -1e30f;
        for (int e = 0; e < 7; e++) mg = fmaxf(mg, Gsc[e]);
        float sum = 0.f;
        float ex[7];
        for (int e = 0; e < 7; e++) { ex[e] = expf(Gsc[e] - mg); sum += ex[e]; }
        float inv = 1.f / sum;
        for (int e = 0; e < 7; e++) {
            float g = ex[e] * inv;
            if (e == epi && e == eqi) g = 0.f;
            gate[row * 7 + e] = g;
        }
    }
}

// ================= 8-phase GEMM template (R6-proven structure) =================
// BM=128, BN=256, BK=64, 512 thr (8 waves 2x4), per-wave 64x64.
// LDS per dbuf: A[128][64] + B[256][64]; 2 dbuf = 96KB.
// T2 swizzle (full 3-bit): elem col ^= (row&7)<<3; conflicts = 0 (R6-verified).
// Counted vmcnt: 6 loads/K-tile staged (4 at p0, 2 at p1); vmcnt(4) once per
// K-tile, vmcnt(0) only at final tile.
template<bool G2>
__global__ __launch_bounds__(512, 2) void gemm8p_kernel(
    const u16* __restrict__ Abase, const u16* __restrict__ Bbase,
    const float* __restrict__ bias, const float* __restrict__ gate,
    void* __restrict__ outp)
{
    constexpr int M = 4096;
    constexpr int K = G2 ? 2048 : 1024;
    constexpr int N = G2 ? 1024 : 2048;
    constexpr int NT = K / 64;
    constexpr int LOG2NT = G2 ? 5 : 4;

    extern __shared__ u16 lds[];

    const int tid = threadIdx.x;
    const int lane = tid & 63;
    const int wid = tid >> 6;
    const int wr = wid >> 2, wc = wid & 3;
    const int ln15 = lane & 15, lnk = (lane >> 4) * 8;

    int bm, bn, e0, nE, grp;
    if constexpr (G2) {
        int id = blockIdx.x;
        int xcd = id & 7, slot = id >> 3;
        grp = xcd & 1;
        bn = slot & 3;
        bm = (slot >> 2) * 4 + (xcd >> 1);
        e0 = grp * 4; nE = grp ? 3 : 4;
    } else {
        int id = blockIdx.x;
        e0 = id >> 8;
        bm = (id & 255) >> 3;
        bn = id & 7;
        nE = 1; grp = 0;
    }
    const int NTtot = nE * NT;

    const int sr = tid >> 3;          // staging row within 64-row sub-unit
    const int sc = (tid & 7) * 8;     // staging col (elems)

    auto stageA = [&](int gt, int buf) {
#pragma unroll
        for (int l = 0; l < 2; ++l) {
            int r = l * 64 + sr;
            int cs = sc ^ ((r & 7) << 3);
            const u16* g = Abase + (G2 ? (size_t)(e0 + (gt >> LOG2NT)) * M * K : (size_t)0)
                         + (size_t)(bm * 128 + r) * K + (gt & (NT - 1)) * 64 + cs;
            gload16(g, lds + buf * 24576 + l * 4096 + tid * 8);
        }
    };
    auto stageB = [&](int gt, int buf, int h) {
#pragma unroll
        for (int l = 0; l < 2; ++l) {
            int rb = h * 128 + l * 64 + sr;
            int cs = sc ^ ((rb & 7) << 3);
            const u16* g = Bbase + (size_t)(e0 + (gt >> LOG2NT)) * N * K
                         + (size_t)(bn * 256 + rb) * K + (gt & (NT - 1)) * 64 + cs;
            gload16(g, lds + buf * 24576 + 8192 + h * 8192 + l * 4096 + tid * 8);
        }
    };
    auto aoff = [&](int mi, int ks) {
        int r = wr * 64 + mi * 16 + ln15;
        int c = ks * 32 + lnk;
        return r * 64 + (c ^ ((r & 7) << 3));
    };
    auto boff = [&](int ni, int ks) {
        int rb = wc * 64 + ni * 16 + ln15;
        int c = ks * 32 + lnk;
        return rb * 64 + (c ^ ((rb & 7) << 3));
    };

    f4 acc[4][4] = {};
    f4 fin[4][4] = {};
    bf8 aA[2][2], bL[2][2], bH[2][2];

    // prologue: tile 0 into buf 0 (6 loads)
    stageA(0, 0); stageB(0, 0, 0); stageB(0, 0, 1);

    for (int gt = 0; gt < NTtot; ++gt) {
        const int cur = gt & 1, nxt = cur ^ 1;
        const bool more = (gt + 1 < NTtot);
        const u16* Ac = lds + cur * 24576;
        const u16* Bc = lds + cur * 24576 + 8192;
        // ---------- phase 0: stage(A',B0') + wait tile gt + Q(m-lo, n-lo)
        if (more) {
            stageA(gt + 1, nxt); stageB(gt + 1, nxt, 0);
            asm volatile("s_waitcnt vmcnt(4)" ::: "memory");
        } else {
            asm volatile("s_waitcnt vmcnt(0)" ::: "memory");
        }
        __builtin_amdgcn_sched_barrier(0);
        __builtin_amdgcn_s_barrier();
        __builtin_amdgcn_sched_barrier(0);
#pragma unroll
        for (int mi = 0; mi < 2; ++mi)
#pragma unroll
            for (int ks = 0; ks < 2; ++ks)
                aA[mi][ks] = *(const bf8*)(Ac + aoff(mi, ks));
#pragma unroll
        for (int ni = 0; ni < 2; ++ni)
#pragma unroll
            for (int ks = 0; ks < 2; ++ks)
                bL[ni][ks] = *(const bf8*)(Bc + boff(ni, ks));
        asm volatile("s_waitcnt lgkmcnt(0)" ::: "memory");
        __builtin_amdgcn_sched_barrier(0);
        __builtin_amdgcn_s_setprio(1);
#pragma unroll
        for (int mi = 0; mi < 2; ++mi)
#pragma unroll
            for (int ni = 0; ni < 2; ++ni)
#pragma unroll
                for (int ks = 0; ks < 2; ++ks)
                    acc[mi][ni] = __builtin_amdgcn_mfma_f32_16x16x32_bf16(aA[mi][ks], bL[ni][ks], acc[mi][ni], 0, 0, 0);
        __builtin_amdgcn_s_setprio(0);
        // ---------- phase 1: stage(B1') + Q(m-lo, n-hi)
        if (more) stageB(gt + 1, nxt, 1);
#pragma unroll
        for (int ni = 0; ni < 2; ++ni)
#pragma unroll
            for (int ks = 0; ks < 2; ++ks)
                bH[ni][ks] = *(const bf8*)(Bc + boff(2 + ni, ks));
        asm volatile("s_waitcnt lgkmcnt(0)" ::: "memory");
        __builtin_amdgcn_sched_barrier(0);
        __builtin_amdgcn_s_setprio(1);
#pragma unroll
        for (int mi = 0; mi < 2; ++mi)
#pragma unroll
            for (int ni = 0; ni < 2; ++ni)
#pragma unroll
                for (int ks = 0; ks < 2; ++ks)
                    acc[mi][2 + ni] = __builtin_amdgcn_mfma_f32_16x16x32_bf16(aA[mi][ks], bH[ni][ks], acc[mi][2 + ni], 0, 0, 0);
        __builtin_amdgcn_s_setprio(0);
        // ---------- phase 2: reload A (m-hi) + Q(m-hi, n-hi)
#pragma unroll
        for (int mi = 0; mi < 2; ++mi)
#pragma unroll
            for (int ks = 0; ks < 2; ++ks)
                aA[mi][ks] = *(const bf8*)(Ac + aoff(2 + mi, ks));
        asm volatile("s_waitcnt lgkmcnt(0)" ::: "memory");
        __builtin_amdgcn_sched_barrier(0);
        __builtin_amdgcn_s_setprio(1);
#pragma unroll
        for (int mi = 0; mi < 2; ++mi)
#pragma unroll
            for (int ni = 0; ni < 2; ++ni)
#pragma unroll
                for (int ks = 0; ks < 2; ++ks)
                    acc[2 + mi][2 + ni] = __builtin_amdgcn_mfma_f32_16x16x32_bf16(aA[mi][ks], bH[ni][ks], acc[2 + mi][2 + ni], 0, 0, 0);
        __builtin_amdgcn_s_setprio(0);
        // ---------- phase 3: barrier (protect buf[cur] before gt+2 stages) + Q(m-hi, n-lo)
        __builtin_amdgcn_sched_barrier(0);
        __builtin_amdgcn_s_barrier();
        __builtin_amdgcn_sched_barrier(0);
        __builtin_amdgcn_s_setprio(1);
#pragma unroll
        for (int mi = 0; mi < 2; ++mi)
#pragma unroll
            for (int ni = 0; ni < 2; ++ni)
#pragma unroll
                for (int ks = 0; ks < 2; ++ks)
                    acc[2 + mi][ni] = __builtin_amdgcn_mfma_f32_16x16x32_bf16(aA[mi][ks], bL[ni][ks], acc[2 + mi][ni], 0, 0, 0);
        __builtin_amdgcn_s_setprio(0);
        __builtin_amdgcn_sched_barrier(0);
        // ---------- expert boundary (G2): gate-weighted accumulate, reset acc
        if constexpr (G2) {
            if ((gt & (NT - 1)) == NT - 1) {
                int e = e0 + (gt >> LOG2NT);
                float bloc[4];
#pragma unroll
                for (int ni = 0; ni < 4; ++ni)
                    bloc[ni] = bias[e * N + bn * 256 + wc * 64 + ni * 16 + ln15];
#pragma unroll
                for (int mi = 0; mi < 4; ++mi)
#pragma unroll
                    for (int i = 0; i < 4; ++i) {
                        int row = bm * 128 + wr * 64 + mi * 16 + (lane >> 4) * 4 + i;
                        float g = gate[row * 7 + e];
#pragma unroll
                        for (int ni = 0; ni < 4; ++ni) {
                            fin[mi][ni][i] += g * fmaxf(acc[mi][ni][i] + bloc[ni], 0.f);
                            acc[mi][ni][i] = 0.f;
                        }
                    }
            }
        }
    }

    // ---------- final epilogue
    if constexpr (G2) {
        float* po = (float*)outp + (size_t)grp * M * N;
#pragma unroll
        for (int mi = 0; mi < 4; ++mi)
#pragma unroll
            for (int i = 0; i < 4; ++i) {
                size_t row = (size_t)(bm * 128 + wr * 64 + mi * 16 + (lane >> 4) * 4 + i);
#pragma unroll
                for (int ni = 0; ni < 4; ++ni)
                    po[row * N + bn * 256 + wc * 64 + ni * 16 + ln15] = fin[mi][ni][i];
            }
    } else {
        float bloc[4];
#pragma unroll
        for (int ni = 0; ni < 4; ++ni)
            bloc[ni] = bias[e0 * N + bn * 256 + wc * 64 + ni * 16 + ln15];
        u16* Hp = (u16*)outp + (size_t)e0 * M * N;
#pragma unroll
        for (int mi = 0; mi < 4; ++mi)
#pragma unroll
            for (int i = 0; i < 4; ++i) {
                size_t row = (size_t)(bm * 128 + wr * 64 + mi * 16 + (lane >> 4) * 4 + i);
#pragma unroll
                for (int ni = 0; ni < 4; ++ni) {
                    // non-temporal: keep the 117MB H stream out of L3 so A/B stay resident
                    __builtin_nontemporal_store(
                        f2bf(fmaxf(acc[mi][ni][i] + bloc[ni], 0.f)),
                        &Hp[row * N + bn * 256 + wc * 64 + ni * 16 + ln15]);
                }
            }
    }
}

// ---------------- combine: out[t] = p0 + p1, t = 0,1 ----------------
__global__ void combine_kernel(const float* __restrict__ p0, const float* __restrict__ p1,
                               float* __restrict__ out, int n4) {
    int i = blockIdx.x * blockDim.x + threadIdx.x;
    int stride = gridDim.x * blockDim.x;
    for (; i < n4; i += stride) {
        float4 a = ((const float4*)p0)[i];
        float4 b = ((const float4*)p1)[i];
        float4 v = make_float4(a.x + b.x, a.y + b.y, a.z + b.z, a.w + b.w);
        ((float4*)out)[i] = v;
        ((float4*)out)[i + n4] = v;
    }
}

extern "C" void kernel_launch(void* const* d_in, const int* in_sizes, int n_in,
                              void* d_out, int out_size, void* d_ws, size_t ws_size,
                              hipStream_t stream) {
    const float* x     = (const float*)d_in[0];
    const int*   scene = (const int*)d_in[1];
    const float* W1    = (const float*)d_in[2];
    const float* b1    = (const float*)d_in[3];
    const float* W2    = (const float*)d_in[4];
    const float* b2    = (const float*)d_in[5];
    const float* S     = (const float*)d_in[6];
    const float* semb  = (const float*)d_in[7];
    float* out = (float*)d_out;

    char* ws = (char*)d_ws;
    float* part = (float*)(ws);                                // 33.5 MB, aliases xb+W1T (dead after gemm1)
    u16*   xb   = (u16*)(ws);                                  // 8,388,608 B
    u16*   W1T  = (u16*)(ws + 8388608);                        // 29,360,128 B
    u16*   W2T  = (u16*)(ws + 37748736);                       // 29,360,128 B
    u16*   Hb   = (u16*)(ws + 67108864);                       // 117,440,512 B
    float* gate = (float*)(ws + 184549376);                    // 114,688 B
    float* ST   = (float*)(ws + 184664064);                    // 216,320 B

    (void)hipFuncSetAttribute(reinterpret_cast<const void*>(gemm8p_kernel<false>),
                              hipFuncAttributeMaxDynamicSharedMemorySize, 98304);
    (void)hipFuncSetAttribute(reinterpret_cast<const void*>(gemm8p_kernel<true>),
                              hipFuncAttributeMaxDynamicSharedMemorySize, 98304);

    cvt_x_kernel<<<2048, 256, 0, stream>>>(x, xb, 4096 * 1024 / 4);
    transpose_cvt_kernel<<<dim3(32, 16, 7), 256, 0, stream>>>(W1, W1T, 1024, 2048);
    transpose_cvt_kernel<<<dim3(16, 32, 7), 256, 0, stream>>>(W2, W2T, 2048, 1024);
    transpose_S_kernel<<<(1040 * 52 + 255) / 256, 256, 0, stream>>>(S, ST);
    gating_kernel<<<1024, 256, 0, stream>>>(x, scene, ST, semb, gate);
    gemm8p_kernel<false><<<1792, 512, 98304, stream>>>(xb, W1T, b1, nullptr, Hb);
    gemm8p_kernel<true><<<256, 512, 98304, stream>>>(Hb, W2T, b2, gate, part);
    combine_kernel<<<2048, 256, 0, stream>>>(part, part + 4096 * 1024, out, 4096 * 1024 / 4);
}